// Round 14
// baseline (132.366 us; speedup 1.0000x reference)
//
#include <hip/hip_runtime.h>

// (B,N,H,NB,NCT) = (8,4096,1024,128,33), H/2 = 512
#define NTOK 4096
#define HDIM 1024
#define HHALF 512
#define NBLK 128
#define CAP 256

typedef __attribute__((ext_vector_type(8))) short short8;
typedef __attribute__((ext_vector_type(4))) float f32x4;
typedef short bf16s;

__device__ __forceinline__ short f2bf(float f) {
    unsigned u = __builtin_bit_cast(unsigned, f);
    u = (u + 0x7fffu + ((u >> 16) & 1u)) >> 16;   // RNE
    return (short)u;
}
__device__ __forceinline__ void gload_lds16(const void* g, void* l) {
    __builtin_amdgcn_global_load_lds(
        (const __attribute__((address_space(1))) unsigned int*)g,
        (__attribute__((address_space(3))) unsigned int*)l, 16, 0, 0);
}
__device__ __forceinline__ float fast_tanh(float v) {
    float e = __expf(2.0f * v);
    return 1.0f - 2.0f / (e + 1.0f);
}

// ---------------------------------------------------------------------------
// Tiled transpose+convert for both weights.
// ---------------------------------------------------------------------------
__global__ void k_tcvt2(const float* __restrict__ W1, const float* __restrict__ Wp,
                        bf16s* __restrict__ w1t, bf16s* __restrict__ wpt) {
    __shared__ float tile[64][65];
    const int by = blockIdx.y;
    const float* in = (by < 8) ? W1 : Wp;
    bf16s* out = (by < 8) ? w1t : wpt;
    const int Nc = (by < 8) ? HHALF : HDIM;
    const int n0 = ((by < 8) ? by : (by - 8)) * 64;
    const int k0 = blockIdx.x * 64;
    const int tx = threadIdx.x & 63, ty = threadIdx.x >> 6;
    #pragma unroll
    for (int i = 0; i < 16; ++i) {
        int r = ty + i * 4;
        tile[r][tx] = in[(size_t)(k0 + r) * Nc + n0 + tx];
    }
    __syncthreads();
    #pragma unroll
    for (int i = 0; i < 16; ++i) {
        int r = ty + i * 4;
        out[(size_t)(n0 + r) * 1024 + k0 + tx] = f2bf(tile[tx][r]);
    }
}

// ---------------------------------------------------------------------------
// Gate GEMM v14 = R13 structure VERBATIM + bf16 xb side-write from the
// already-converted CVTWR registers (ctile==0 wgs only; each row covered
// exactly once). Stores are issued AFTER the B(t+1) glls, so the compiler's
// rA-dependency wait still retires exactly B(t)+Af32(t+1) — counted-staging
// invariant unchanged; stores drain at the final vmcnt(0).
// 128x256 tile, BK=32, 4 waves (1m x 4n), acc[8][4], 48 KB LDS, 2 wgs/CU,
// ONE barrier per K-iter.
// ---------------------------------------------------------------------------
__global__ __launch_bounds__(256, 2) void k_gemmv(
    const float* __restrict__ x, const bf16s* __restrict__ w1t,
    const float* __restrict__ b1, const float* __restrict__ w2,
    float* __restrict__ partial, bf16s* __restrict__ xb)
{
    __shared__ alignas(16) bf16s As[2][128 * 32];   //  16 KB
    __shared__ alignas(16) bf16s Bs[2][256 * 32];   //  32 KB

    const int tid = threadIdx.x;
    const int lane = tid & 63;
    const int wn = tid >> 6;                        // 0..3 (col group)
    const int phys = blockIdx.x;
    const int logical = (phys & 7) * 64 + (phys >> 3);  // 512 = 8*64 bijective
    const int rp = logical >> 1;                    // 0..255
    const int ctile = logical & 1;
    const int row0 = rp * 128;
    const int col0 = ctile * 256;
    const int c0 = lane & 15, khalf = lane >> 4;

    // ---- A staging (f32 -> regs -> cvt -> ds_write, swizzled dest) ----
    const int ar = tid >> 1, ah = tid & 1;          // row 0..127, 16-col half
    const float* aF = &x[(size_t)(row0 + ar) * HDIM + ah * 16];
    bf16s* xbrow = &xb[(size_t)(row0 + ar) * HDIM + ah * 16];
    const bool wxb = (ctile == 0);
    const int akey = (ar >> 1) & 3;
    const int aslot0 = ((2 * ah) ^ akey) * 8;       // dest chunk slots (shorts)
    const int aslot1 = ((2 * ah + 1) ^ akey) * 8;
    const int arow32 = ar * 32;

    // ---- B staging (gll, pre-swizzled source) ----
    const int sj = (lane & 3) ^ ((lane >> 3) & 3);
    const bf16s* bS[4];
    int bdst[4];
    #pragma unroll
    for (int q = 0; q < 4; ++q) {
        int rb = wn * 64 + q * 16 + (lane >> 2);
        bS[q] = &w1t[(size_t)(col0 + rb) * HDIM + sj * 8];
        bdst[q] = (wn * 64 + q * 16) * 32 + lane * 8;
    }

    // ---- fragment read offsets ----
    const int fkey = (c0 >> 1) & 3;
    const int ach = (khalf ^ fkey) * 8;
    const int arA = c0 * 32 + ach;                  // + mf*16*32
    const int brB = (wn * 64 + c0) * 32 + ach;      // + nf*16*32

    f32x4 acc[8][4] = {};
    float4 rA0, rA1, rA2, rA3;

#define LOAD_RA(T) do {                                               \
        rA0 = *reinterpret_cast<const float4*>(aF + (T) * 32);        \
        rA1 = *reinterpret_cast<const float4*>(aF + (T) * 32 + 4);    \
        rA2 = *reinterpret_cast<const float4*>(aF + (T) * 32 + 8);    \
        rA3 = *reinterpret_cast<const float4*>(aF + (T) * 32 + 12);   \
    } while (0)
#define CVTWR(BUF, T) do {                                            \
        short h_[16] = {f2bf(rA0.x), f2bf(rA0.y), f2bf(rA0.z), f2bf(rA0.w), \
                        f2bf(rA1.x), f2bf(rA1.y), f2bf(rA1.z), f2bf(rA1.w), \
                        f2bf(rA2.x), f2bf(rA2.y), f2bf(rA2.z), f2bf(rA2.w), \
                        f2bf(rA3.x), f2bf(rA3.y), f2bf(rA3.z), f2bf(rA3.w)};\
        *reinterpret_cast<int4*>(&As[BUF][arow32 + aslot0]) =         \
            *reinterpret_cast<const int4*>(&h_[0]);                   \
        *reinterpret_cast<int4*>(&As[BUF][arow32 + aslot1]) =         \
            *reinterpret_cast<const int4*>(&h_[8]);                   \
        if (wxb) {                                                    \
            *reinterpret_cast<int4*>(xbrow + (size_t)(T) * 32) =      \
                *reinterpret_cast<const int4*>(&h_[0]);               \
            *reinterpret_cast<int4*>(xbrow + (size_t)(T) * 32 + 8) =  \
                *reinterpret_cast<const int4*>(&h_[8]);               \
        }                                                             \
    } while (0)

    // ---- prologue: A(0)+B(0) -> buf0; rA = A(1) ----
    LOAD_RA(0);
    CVTWR(0, 0);
    #pragma unroll
    for (int q = 0; q < 4; ++q)
        gload_lds16(bS[q], &Bs[0][bdst[q]]);
    LOAD_RA(1);

    for (int t = 0; t < 32; ++t) {
        const int c = t & 1;
        if (t < 31) {
            // stage tile t+1 into buf c^1 (certified dead: read at t-1, barrier since)
            #pragma unroll
            for (int q = 0; q < 4; ++q)
                gload_lds16(bS[q] + (t + 1) * 32, &Bs[c ^ 1][bdst[q]]);
            __builtin_amdgcn_sched_barrier(0);   // pin gll-before-CVTWR (FIFO order)
            CVTWR(c ^ 1, t + 1);                 // implicit vmcnt: retires B(t)+Af32(t+1)
            if (t < 30) LOAD_RA(t + 2);
        } else {
            asm volatile("s_waitcnt vmcnt(0)" ::: "memory");
        }
        asm volatile("s_waitcnt lgkmcnt(0)" ::: "memory");  // my ds_writes done
        __builtin_amdgcn_sched_barrier(0);
        __builtin_amdgcn_s_barrier();                       // tile t certified

        short8 av[8], bvv[4];
        #pragma unroll
        for (int mf = 0; mf < 8; ++mf)
            av[mf] = *reinterpret_cast<const short8*>(&As[c][arA + mf * 512]);
        #pragma unroll
        for (int nf = 0; nf < 4; ++nf)
            bvv[nf] = *reinterpret_cast<const short8*>(&Bs[c][brB + nf * 512]);
        asm volatile("s_waitcnt lgkmcnt(0)" ::: "memory");
        __builtin_amdgcn_sched_barrier(0);

        __builtin_amdgcn_s_setprio(1);
        #pragma unroll
        for (int nf = 0; nf < 4; ++nf)
            #pragma unroll
            for (int mf = 0; mf < 8; ++mf)
                acc[mf][nf] = __builtin_amdgcn_mfma_f32_16x16x32_bf16(av[mf], bvv[nf], acc[mf][nf], 0, 0, 0);
        __builtin_amdgcn_s_setprio(0);
    }
#undef LOAD_RA
#undef CVTWR

    // epilogue: per-row dot of tanh(h)*W2 over this wave's 64 cols.
    __syncthreads();
    float* gp = reinterpret_cast<float*>(&As[0][0]);
    float b1v[4], w2v[4];
    #pragma unroll
    for (int nf = 0; nf < 4; ++nf) {
        int gc = col0 + wn * 64 + nf * 16 + c0;
        b1v[nf] = b1[gc];
        w2v[nf] = w2[gc];
    }
    #pragma unroll
    for (int mf = 0; mf < 8; ++mf) {
        #pragma unroll
        for (int reg = 0; reg < 4; ++reg) {
            float s = 0.f;
            #pragma unroll
            for (int nf = 0; nf < 4; ++nf)
                s += fast_tanh(acc[mf][nf][reg] + b1v[nf]) * w2v[nf];
            s += __shfl_xor(s, 1); s += __shfl_xor(s, 2);
            s += __shfl_xor(s, 4); s += __shfl_xor(s, 8);
            if (c0 == 0) gp[wn * 128 + mf * 16 + khalf * 4 + reg] = s;
        }
    }
    __syncthreads();
    if (tid < 128)
        partial[(size_t)ctile * 32768 + row0 + tid] =
            gp[tid] + gp[128 + tid] + gp[256 + tid] + gp[384 + tid];
}

// ---------------------------------------------------------------------------
// Single-pass per-(b,block): sums the 2 gate partials for member tokens,
// online-softmax stats, ordered lists.
// ---------------------------------------------------------------------------
__global__ void k_blocks(const int* __restrict__ block_ids, const unsigned char* __restrict__ pad,
                         const float* __restrict__ part, const float* __restrict__ b2,
                         float* __restrict__ gate, const int* __restrict__ ct,
                         const float* __restrict__ ct_emb,
                         int* __restrict__ counts, float* __restrict__ mblk,
                         float* __restrict__ wscale, int* __restrict__ lists,
                         float* __restrict__ out_hasb)
{
    const int blk = blockIdx.x;
    const int b = blk >> 7, k = blk & 127;
    const int lane = threadIdx.x;
    const int base = b * NTOK;
    const int lbase = blk * CAP;
    const unsigned long long ltmask = (1ull << lane) - 1ull;
    const float b2v = b2[0];

    float m = -__builtin_inff();
    float s = 0.f;
    int pos = 0;
    for (int t0 = 0; t0 < NTOK; t0 += 64) {
        int t = t0 + lane;
        bool mt = (block_ids[base + t] == k) && (pad[base + t] == 0);
        unsigned long long mask = __ballot(mt);
        if (mt) {
            int r = base + t;
            float g = part[r] + part[32768 + r] + b2v;
            gate[r] = g;   // each valid token belongs to exactly one block
            int my = pos + __popcll(mask & ltmask);
            if (my < CAP) lists[lbase + my] = t;
            float mn = fmaxf(m, g);
            s = s * __expf(m - mn) + __expf(g - mn);
            m = mn;
        }
        pos += __popcll(mask);
    }
    #pragma unroll
    for (int off = 1; off < 64; off <<= 1) {
        float om = __shfl_xor(m, off);
        float os = __shfl_xor(s, off);
        float mn = fmaxf(m, om);
        float sa = (m == -__builtin_inff()) ? 0.f : s * __expf(m - mn);
        float sb = (om == -__builtin_inff()) ? 0.f : os * __expf(om - mn);
        s = sa + sb;
        m = mn;
    }
    if (lane == 0) {
        counts[blk] = pos;
        mblk[blk] = (pos > 0) ? m : 0.f;
        float mod = 1.0f + 0.1f * ct_emb[ct[b] * NBLK + k];
        wscale[blk] = (pos > 0 && s > 0.f) ? (mod / fmaxf(s, 1e-30f)) : 0.f;
        out_hasb[blk] = (pos > 0) ? 1.f : 0.f;
    }
}

// ---------------------------------------------------------------------------
// Pooling from bf16 xb: pooled[b,k,:] = wscale * sum_n exp(gate[n]-m) * xb[b,n,:]
// ---------------------------------------------------------------------------
__global__ void k_pool(const bf16s* __restrict__ xb, const float* __restrict__ gate,
                       const int* __restrict__ lists, const int* __restrict__ counts,
                       const float* __restrict__ mblk, const float* __restrict__ wscale,
                       bf16s* __restrict__ pooled)
{
    const int blk = blockIdx.x;
    const int b = blk >> 7;
    const int tid = threadIdx.x;
    const int base = b * NTOK;
    const int cnt = min(counts[blk], CAP);
    const int lbase = blk * CAP;
    const float m = mblk[blk], ws = wscale[blk];

    float4 acc = {0.f, 0.f, 0.f, 0.f};
    for (int i = 0; i < cnt; ++i) {
        int n = lists[lbase + i];
        float w = __expf(gate[base + n] - m);
        int2 rv = *reinterpret_cast<const int2*>(&xb[(size_t)(base + n) * HDIM + tid * 4]);
        short s4[4];
        *reinterpret_cast<int2*>(s4) = rv;
        unsigned u0 = ((unsigned)(unsigned short)s4[0]) << 16;
        unsigned u1 = ((unsigned)(unsigned short)s4[1]) << 16;
        unsigned u2 = ((unsigned)(unsigned short)s4[2]) << 16;
        unsigned u3 = ((unsigned)(unsigned short)s4[3]) << 16;
        acc.x += w * __builtin_bit_cast(float, u0);
        acc.y += w * __builtin_bit_cast(float, u1);
        acc.z += w * __builtin_bit_cast(float, u2);
        acc.w += w * __builtin_bit_cast(float, u3);
    }
    short o[4] = {f2bf(acc.x * ws), f2bf(acc.y * ws), f2bf(acc.z * ws), f2bf(acc.w * ws)};
    *reinterpret_cast<int2*>(&pooled[(size_t)blk * HDIM + tid * 4]) =
        *reinterpret_cast<const int2*>(o);
}

// ---------------------------------------------------------------------------
// GEMM2: y = pooled @ Wp + bp. 1024^3. 64x64 tiles, 4 waves, dbuf + gll,
// counted-vmcnt schedule.
// ---------------------------------------------------------------------------
__global__ __launch_bounds__(256) void k_gemm2(
    const bf16s* __restrict__ pooled, const bf16s* __restrict__ wpt,
    const float* __restrict__ bp, float* __restrict__ y)
{
    __shared__ alignas(16) bf16s As[2][64 * 32];
    __shared__ alignas(16) bf16s Bs[2][64 * 32];
    const int tid = threadIdx.x;
    const int lane = tid & 63;
    const int wv = tid >> 6;
    const int wr = wv >> 1, wc = wv & 1;
    const int row0 = (blockIdx.x >> 4) * 64, col0 = (blockIdx.x & 15) * 64;
    const int c0 = lane & 15, khalf = lane >> 4;

    const int sr = wv * 16 + (lane >> 2);
    const int sj = (lane & 3) ^ ((sr >> 1) & 3);
    const int sdst = (wv * 16) * 32 + lane * 8;
    const bf16s* srcA = &pooled[(size_t)(row0 + sr) * 1024 + sj * 8];
    const bf16s* srcB = &wpt[(size_t)(col0 + sr) * 1024 + sj * 8];

    f32x4 acc[2][2] = {};

    gload_lds16(srcA, &As[0][sdst]);
    gload_lds16(srcB, &Bs[0][sdst]);

    for (int t = 0; t < 32; ++t) {
        const int cur = t & 1;
        if (t < 31) {
            gload_lds16(srcA + (t + 1) * 32, &As[cur ^ 1][sdst]);
            gload_lds16(srcB + (t + 1) * 32, &Bs[cur ^ 1][sdst]);
            asm volatile("s_waitcnt vmcnt(2)" ::: "memory");
        } else {
            asm volatile("s_waitcnt vmcnt(0)" ::: "memory");
        }
        __builtin_amdgcn_s_barrier();
        __builtin_amdgcn_sched_barrier(0);
        #pragma unroll
        for (int mf = 0; mf < 2; ++mf) {
            int ra = wr * 32 + mf * 16 + c0;
            short8 av = *reinterpret_cast<const short8*>(
                &As[cur][ra * 32 + ((khalf ^ ((ra >> 1) & 3)) * 8)]);
            #pragma unroll
            for (int nf = 0; nf < 2; ++nf) {
                int rb = wc * 32 + nf * 16 + c0;
                short8 bv = *reinterpret_cast<const short8*>(
                    &Bs[cur][rb * 32 + ((khalf ^ ((rb >> 1) & 3)) * 8)]);
                acc[mf][nf] = __builtin_amdgcn_mfma_f32_16x16x32_bf16(av, bv, acc[mf][nf], 0, 0, 0);
            }
        }
        asm volatile("s_waitcnt lgkmcnt(0)" ::: "memory");
        __builtin_amdgcn_sched_barrier(0);
        __builtin_amdgcn_s_barrier();
    }
    #pragma unroll
    for (int mf = 0; mf < 2; ++mf)
        #pragma unroll
        for (int nf = 0; nf < 2; ++nf)
            #pragma unroll
            for (int reg = 0; reg < 4; ++reg) {
                int grow = row0 + wr * 32 + mf * 16 + khalf * 4 + reg;
                int gcol = col0 + wc * 32 + nf * 16 + c0;
                y[(size_t)grow * 1024 + gcol] = acc[mf][nf][reg] + bp[gcol];
            }
}

// ---------------------------------------------------------------------------
// LayerNorm + ELU + present-mask.
// ---------------------------------------------------------------------------
__global__ void k_lnelu(const float* __restrict__ y, const float* __restrict__ ln_g,
                        const float* __restrict__ ln_b, const int* __restrict__ counts,
                        float* __restrict__ outp)
{
    const int row = blockIdx.x;
    const int k = row & 127;
    const int tid = threadIdx.x;

    float4 v = *reinterpret_cast<const float4*>(&y[(size_t)row * 1024 + tid * 4]);
    float s = v.x + v.y + v.z + v.w;
    float ss = v.x * v.x + v.y * v.y + v.z * v.z + v.w * v.w;
    #pragma unroll
    for (int off = 32; off; off >>= 1) { s += __shfl_xor(s, off); ss += __shfl_xor(ss, off); }

    __shared__ float sbuf[4], ssbuf[4];
    int wv = tid >> 6;
    if ((tid & 63) == 0) { sbuf[wv] = s; ssbuf[wv] = ss; }
    __syncthreads();
    s = sbuf[0] + sbuf[1] + sbuf[2] + sbuf[3];
    ss = ssbuf[0] + ssbuf[1] + ssbuf[2] + ssbuf[3];

    float mu = s * (1.f / 1024.f);
    float var = ss * (1.f / 1024.f) - mu * mu;
    float rstd = rsqrtf(var + 1e-5f);

    bool pres = false;
    #pragma unroll
    for (int bb = 0; bb < 8; ++bb) pres = pres || (counts[bb * NBLK + k] > 0);

    float4 g4 = *reinterpret_cast<const float4*>(&ln_g[tid * 4]);
    float4 b4 = *reinterpret_cast<const float4*>(&ln_b[tid * 4]);
    float vals[4] = {v.x, v.y, v.z, v.w};
    float gs[4] = {g4.x, g4.y, g4.z, g4.w};
    float bs[4] = {b4.x, b4.y, b4.z, b4.w};
    float4 o;
    float* op = &o.x;
    #pragma unroll
    for (int j = 0; j < 4; ++j) {
        float t = (vals[j] - mu) * rstd * gs[j] + bs[j];
        t = (t > 0.f) ? t : expm1f(t);
        op[j] = pres ? t : 0.f;
    }
    *reinterpret_cast<float4*>(&outp[(size_t)row * 1024 + tid * 4]) = o;
}

// ---------------------------------------------------------------------------
extern "C" void kernel_launch(void* const* d_in, const int* in_sizes, int n_in,
                              void* d_out, int out_size, void* d_ws, size_t ws_size,
                              hipStream_t stream)
{
    const float* x      = (const float*)d_in[0];
    const int*   ct     = (const int*)d_in[1];
    const int*   bids   = (const int*)d_in[2];
    const unsigned char* pad = (const unsigned char*)d_in[3];
    const float* W1     = (const float*)d_in[4];
    const float* b1     = (const float*)d_in[5];
    const float* W2     = (const float*)d_in[6];
    const float* b2     = (const float*)d_in[7];
    const float* ct_emb = (const float*)d_in[8];
    const float* Wp     = (const float*)d_in[9];
    const float* bp     = (const float*)d_in[10];
    const float* ln_g   = (const float*)d_in[11];
    const float* ln_b   = (const float*)d_in[12];
    float* outF = (float*)d_out;

    char* ws = (char*)d_ws;
    bf16s* w1t    = (bf16s*)(ws + 0);          //  1,048,576
    bf16s* wpt    = (bf16s*)(ws + 1048576);    //  2,097,152 -> 3,145,728
    float* gate   = (float*)(ws + 3145728);    //    131,072 -> 3,276,800
    float* part   = (float*)(ws + 3276800);    //    524,288 -> 3,801,088 (2 used)
    float* mblk   = (float*)(ws + 3801088);
    float* wscal  = (float*)(ws + 3805184);
    int*   counts = (int*)  (ws + 3809280);
    int*   lists  = (int*)  (ws + 3813376);    //  1,048,576 -> 4,861,952
    bf16s* pooled = (bf16s*)(ws + 4861952);    //  2,097,152 -> 6,959,104
    float* ybuf   = (float*)(ws + 6959104);    //  4,194,304 -> 11,153,408
    bf16s* xb     = (bf16s*)(ws + 11153408);   // 67,108,864 -> 78,262,272

    k_tcvt2<<<dim3(16, 24), 256, 0, stream>>>(W1, Wp, w1t, wpt);
    k_gemmv<<<512, 256, 0, stream>>>(x, w1t, b1, W2, part, xb);
    k_blocks<<<1024, 64, 0, stream>>>(bids, pad, part, b2, gate, ct, ct_emb,
                                      counts, mblk, wscal, lists,
                                      outF + (size_t)8 * NBLK * HDIM);
    k_pool<<<1024, 256, 0, stream>>>(xb, gate, lists, counts, mblk, wscal, pooled);
    k_gemm2<<<256, 256, 0, stream>>>(pooled, wpt, bp, ybuf);
    k_lnelu<<<1024, 256, 0, stream>>>(ybuf, ln_g, ln_b, counts, outF);
}

// Round 15
// 126.131 us; speedup vs baseline: 1.0494x; 1.0494x over previous
//
#include <hip/hip_runtime.h>

// (B,N,H,NB,NCT) = (8,4096,1024,128,33), H/2 = 512
#define NTOK 4096
#define HDIM 1024
#define HHALF 512
#define NBLK 128
#define CAP 256

typedef __attribute__((ext_vector_type(8))) short short8;
typedef __attribute__((ext_vector_type(4))) float f32x4;
typedef short bf16s;

__device__ __forceinline__ short f2bf(float f) {
    unsigned u = __builtin_bit_cast(unsigned, f);
    u = (u + 0x7fffu + ((u >> 16) & 1u)) >> 16;   // RNE
    return (short)u;
}
__device__ __forceinline__ void gload_lds16(const void* g, void* l) {
    __builtin_amdgcn_global_load_lds(
        (const __attribute__((address_space(1))) unsigned int*)g,
        (__attribute__((address_space(3))) unsigned int*)l, 16, 0, 0);
}
__device__ __forceinline__ float fast_tanh(float v) {
    float e = __expf(2.0f * v);
    return 1.0f - 2.0f / (e + 1.0f);
}

// ---------------------------------------------------------------------------
// Tiled transpose+convert for both weights.
// ---------------------------------------------------------------------------
__global__ void k_tcvt2(const float* __restrict__ W1, const float* __restrict__ Wp,
                        bf16s* __restrict__ w1t, bf16s* __restrict__ wpt) {
    __shared__ float tile[64][65];
    const int by = blockIdx.y;
    const float* in = (by < 8) ? W1 : Wp;
    bf16s* out = (by < 8) ? w1t : wpt;
    const int Nc = (by < 8) ? HHALF : HDIM;
    const int n0 = ((by < 8) ? by : (by - 8)) * 64;
    const int k0 = blockIdx.x * 64;
    const int tx = threadIdx.x & 63, ty = threadIdx.x >> 6;
    #pragma unroll
    for (int i = 0; i < 16; ++i) {
        int r = ty + i * 4;
        tile[r][tx] = in[(size_t)(k0 + r) * Nc + n0 + tx];
    }
    __syncthreads();
    #pragma unroll
    for (int i = 0; i < 16; ++i) {
        int r = ty + i * 4;
        out[(size_t)(n0 + r) * 1024 + k0 + tx] = f2bf(tile[tx][r]);
    }
}

// ---------------------------------------------------------------------------
// Gate GEMM v13 (best-measured: 81us): 128x256 tile, BK=32, 256 thr = 4 waves
// (1m x 4n), wave-out 128x64 = acc[8][4]. 48 KB LDS + 240 regs/wave ->
// 2 wgs/CU (cross-wg overlap hides barrier/vmcnt stalls; m114 mechanism).
// ONE barrier per K-iter (32 total). Counted-vmcnt by construction:
//   iter t FIFO (oldest->newest): [B(t)x4, Af32(t+1)x4]
//   issue B(t+1)x4           -> [B(t)4, Af32(t+1)4, B(t+1)4]
//   CVTWR uses Af32(t+1)     -> compiler waits vmcnt(4): retires B(t)+Af32(t+1),
//                               keeps B(t+1) in flight (never drains pipeline)
//   issue Af32(t+2)          -> steady state [B(t+1)4, Af32(t+2)4]
//   lgkmcnt(0)+barrier certifies B(t) gll writes and A(t) CVTWR writes.
// A f32->bf16 inline (no xcvt pass, NO xb side-write — measured regression).
// Swizzle: LDS chunk slot s holds source chunk s^((row>>1)&3); reads XOR same.
// ---------------------------------------------------------------------------
__global__ __launch_bounds__(256, 2) void k_gemmv(
    const float* __restrict__ x, const bf16s* __restrict__ w1t,
    const float* __restrict__ b1, const float* __restrict__ w2,
    float* __restrict__ partial)
{
    __shared__ alignas(16) bf16s As[2][128 * 32];   //  16 KB
    __shared__ alignas(16) bf16s Bs[2][256 * 32];   //  32 KB

    const int tid = threadIdx.x;
    const int lane = tid & 63;
    const int wn = tid >> 6;                        // 0..3 (col group)
    const int phys = blockIdx.x;
    const int logical = (phys & 7) * 64 + (phys >> 3);  // 512 = 8*64 bijective
    const int rp = logical >> 1;                    // 0..255
    const int ctile = logical & 1;
    const int row0 = rp * 128;
    const int col0 = ctile * 256;
    const int c0 = lane & 15, khalf = lane >> 4;

    // ---- A staging (f32 -> regs -> cvt -> ds_write, swizzled dest) ----
    const int ar = tid >> 1, ah = tid & 1;          // row 0..127, 16-col half
    const float* aF = &x[(size_t)(row0 + ar) * HDIM + ah * 16];
    const int akey = (ar >> 1) & 3;
    const int aslot0 = ((2 * ah) ^ akey) * 8;       // dest chunk slots (shorts)
    const int aslot1 = ((2 * ah + 1) ^ akey) * 8;
    const int arow32 = ar * 32;

    // ---- B staging (gll, pre-swizzled source) ----
    const int sj = (lane & 3) ^ ((lane >> 3) & 3);
    const bf16s* bS[4];
    int bdst[4];
    #pragma unroll
    for (int q = 0; q < 4; ++q) {
        int rb = wn * 64 + q * 16 + (lane >> 2);
        bS[q] = &w1t[(size_t)(col0 + rb) * HDIM + sj * 8];
        bdst[q] = (wn * 64 + q * 16) * 32 + lane * 8;
    }

    // ---- fragment read offsets ----
    const int fkey = (c0 >> 1) & 3;                 // == ((mf*16+c0)>>1)&3
    const int ach = (khalf ^ fkey) * 8;
    const int arA = c0 * 32 + ach;                  // + mf*16*32
    const int brB = (wn * 64 + c0) * 32 + ach;      // + nf*16*32 (same key math)

    f32x4 acc[8][4] = {};
    float4 rA0, rA1, rA2, rA3;

#define LOAD_RA(T) do {                                               \
        rA0 = *reinterpret_cast<const float4*>(aF + (T) * 32);        \
        rA1 = *reinterpret_cast<const float4*>(aF + (T) * 32 + 4);    \
        rA2 = *reinterpret_cast<const float4*>(aF + (T) * 32 + 8);    \
        rA3 = *reinterpret_cast<const float4*>(aF + (T) * 32 + 12);   \
    } while (0)
#define CVTWR(BUF) do {                                               \
        short h_[16] = {f2bf(rA0.x), f2bf(rA0.y), f2bf(rA0.z), f2bf(rA0.w), \
                        f2bf(rA1.x), f2bf(rA1.y), f2bf(rA1.z), f2bf(rA1.w), \
                        f2bf(rA2.x), f2bf(rA2.y), f2bf(rA2.z), f2bf(rA2.w), \
                        f2bf(rA3.x), f2bf(rA3.y), f2bf(rA3.z), f2bf(rA3.w)};\
        *reinterpret_cast<int4*>(&As[BUF][arow32 + aslot0]) =         \
            *reinterpret_cast<const int4*>(&h_[0]);                   \
        *reinterpret_cast<int4*>(&As[BUF][arow32 + aslot1]) =         \
            *reinterpret_cast<const int4*>(&h_[8]);                   \
    } while (0)

    // ---- prologue: A(0)+B(0) -> buf0; rA = A(1) ----
    LOAD_RA(0);
    CVTWR(0);
    #pragma unroll
    for (int q = 0; q < 4; ++q)
        gload_lds16(bS[q], &Bs[0][bdst[q]]);
    LOAD_RA(1);

    for (int t = 0; t < 32; ++t) {
        const int c = t & 1;
        if (t < 31) {
            // stage tile t+1 into buf c^1 (certified dead: read at t-1, barrier since)
            #pragma unroll
            for (int q = 0; q < 4; ++q)
                gload_lds16(bS[q] + (t + 1) * 32, &Bs[c ^ 1][bdst[q]]);
            __builtin_amdgcn_sched_barrier(0);   // pin gll-before-CVTWR (keeps B(t+1) newest)
            CVTWR(c ^ 1);                        // implicit vmcnt(4): retires B(t)+Af32(t+1)
            if (t < 30) LOAD_RA(t + 2);
        } else {
            asm volatile("s_waitcnt vmcnt(0)" ::: "memory");
        }
        asm volatile("s_waitcnt lgkmcnt(0)" ::: "memory");  // A(t) (+just-issued) writes done
        __builtin_amdgcn_sched_barrier(0);
        __builtin_amdgcn_s_barrier();                       // tile t certified for all waves

        short8 av[8], bvv[4];
        #pragma unroll
        for (int mf = 0; mf < 8; ++mf)
            av[mf] = *reinterpret_cast<const short8*>(&As[c][arA + mf * 512]);
        #pragma unroll
        for (int nf = 0; nf < 4; ++nf)
            bvv[nf] = *reinterpret_cast<const short8*>(&Bs[c][brB + nf * 512]);
        asm volatile("s_waitcnt lgkmcnt(0)" ::: "memory");
        __builtin_amdgcn_sched_barrier(0);

        __builtin_amdgcn_s_setprio(1);
        #pragma unroll
        for (int nf = 0; nf < 4; ++nf)
            #pragma unroll
            for (int mf = 0; mf < 8; ++mf)
                acc[mf][nf] = __builtin_amdgcn_mfma_f32_16x16x32_bf16(av[mf], bvv[nf], acc[mf][nf], 0, 0, 0);
        __builtin_amdgcn_s_setprio(0);
        // no trailing barrier: my ds_reads are consumed before my next-iter barrier
        // arrival; writes to buf c resume only after TWO more top barriers (t+2).
    }
#undef LOAD_RA
#undef CVTWR

    // epilogue: per-row dot of tanh(h)*W2 over this wave's 64 cols.
    // gp[4][128] aliased into As (all LDS traffic drained: lgkm+barrier path).
    __syncthreads();
    float* gp = reinterpret_cast<float*>(&As[0][0]);
    float b1v[4], w2v[4];
    #pragma unroll
    for (int nf = 0; nf < 4; ++nf) {
        int gc = col0 + wn * 64 + nf * 16 + c0;
        b1v[nf] = b1[gc];
        w2v[nf] = w2[gc];
    }
    #pragma unroll
    for (int mf = 0; mf < 8; ++mf) {
        #pragma unroll
        for (int reg = 0; reg < 4; ++reg) {
            float s = 0.f;
            #pragma unroll
            for (int nf = 0; nf < 4; ++nf)
                s += fast_tanh(acc[mf][nf][reg] + b1v[nf]) * w2v[nf];
            s += __shfl_xor(s, 1); s += __shfl_xor(s, 2);
            s += __shfl_xor(s, 4); s += __shfl_xor(s, 8);
            if (c0 == 0) gp[wn * 128 + mf * 16 + khalf * 4 + reg] = s;
        }
    }
    __syncthreads();
    if (tid < 128)
        partial[(size_t)ctile * 32768 + row0 + tid] =
            gp[tid] + gp[128 + tid] + gp[256 + tid] + gp[384 + tid];
}

// ---------------------------------------------------------------------------
// Single-pass per-(b,block): sums the 2 gate partials for member tokens,
// online-softmax stats, ordered lists.
// ---------------------------------------------------------------------------
__global__ void k_blocks(const int* __restrict__ block_ids, const unsigned char* __restrict__ pad,
                         const float* __restrict__ part, const float* __restrict__ b2,
                         float* __restrict__ gate, const int* __restrict__ ct,
                         const float* __restrict__ ct_emb,
                         int* __restrict__ counts, float* __restrict__ mblk,
                         float* __restrict__ wscale, int* __restrict__ lists,
                         float* __restrict__ out_hasb)
{
    const int blk = blockIdx.x;
    const int b = blk >> 7, k = blk & 127;
    const int lane = threadIdx.x;
    const int base = b * NTOK;
    const int lbase = blk * CAP;
    const unsigned long long ltmask = (1ull << lane) - 1ull;
    const float b2v = b2[0];

    float m = -__builtin_inff();
    float s = 0.f;
    int pos = 0;
    for (int t0 = 0; t0 < NTOK; t0 += 64) {
        int t = t0 + lane;
        bool mt = (block_ids[base + t] == k) && (pad[base + t] == 0);
        unsigned long long mask = __ballot(mt);
        if (mt) {
            int r = base + t;
            float g = part[r] + part[32768 + r] + b2v;
            gate[r] = g;   // each valid token belongs to exactly one block
            int my = pos + __popcll(mask & ltmask);
            if (my < CAP) lists[lbase + my] = t;
            float mn = fmaxf(m, g);
            s = s * __expf(m - mn) + __expf(g - mn);
            m = mn;
        }
        pos += __popcll(mask);
    }
    #pragma unroll
    for (int off = 1; off < 64; off <<= 1) {
        float om = __shfl_xor(m, off);
        float os = __shfl_xor(s, off);
        float mn = fmaxf(m, om);
        float sa = (m == -__builtin_inff()) ? 0.f : s * __expf(m - mn);
        float sb = (om == -__builtin_inff()) ? 0.f : os * __expf(om - mn);
        s = sa + sb;
        m = mn;
    }
    if (lane == 0) {
        counts[blk] = pos;
        mblk[blk] = (pos > 0) ? m : 0.f;
        float mod = 1.0f + 0.1f * ct_emb[ct[b] * NBLK + k];
        wscale[blk] = (pos > 0 && s > 0.f) ? (mod / fmaxf(s, 1e-30f)) : 0.f;
        out_hasb[blk] = (pos > 0) ? 1.f : 0.f;
    }
}

// ---------------------------------------------------------------------------
// Pooling from f32 x (L3-resident; one-pass read at roofline).
// ---------------------------------------------------------------------------
__global__ void k_pool(const float* __restrict__ x, const float* __restrict__ gate,
                       const int* __restrict__ lists, const int* __restrict__ counts,
                       const float* __restrict__ mblk, const float* __restrict__ wscale,
                       bf16s* __restrict__ pooled)
{
    const int blk = blockIdx.x;
    const int b = blk >> 7;
    const int tid = threadIdx.x;
    const int base = b * NTOK;
    const int cnt = min(counts[blk], CAP);
    const int lbase = blk * CAP;
    const float m = mblk[blk], ws = wscale[blk];

    float4 acc = {0.f, 0.f, 0.f, 0.f};
    for (int i = 0; i < cnt; ++i) {
        int n = lists[lbase + i];
        float w = __expf(gate[base + n] - m);
        float4 xv = *reinterpret_cast<const float4*>(&x[(size_t)(base + n) * HDIM + tid * 4]);
        acc.x += w * xv.x; acc.y += w * xv.y; acc.z += w * xv.z; acc.w += w * xv.w;
    }
    short o[4] = {f2bf(acc.x * ws), f2bf(acc.y * ws), f2bf(acc.z * ws), f2bf(acc.w * ws)};
    *reinterpret_cast<int2*>(&pooled[(size_t)blk * HDIM + tid * 4]) =
        *reinterpret_cast<const int2*>(o);
}

// ---------------------------------------------------------------------------
// GEMM2: y = pooled @ Wp + bp. 1024^3. 64x64 tiles, 4 waves, dbuf + gll,
// counted-vmcnt schedule.
// ---------------------------------------------------------------------------
__global__ __launch_bounds__(256) void k_gemm2(
    const bf16s* __restrict__ pooled, const bf16s* __restrict__ wpt,
    const float* __restrict__ bp, float* __restrict__ y)
{
    __shared__ alignas(16) bf16s As[2][64 * 32];
    __shared__ alignas(16) bf16s Bs[2][64 * 32];
    const int tid = threadIdx.x;
    const int lane = tid & 63;
    const int wv = tid >> 6;
    const int wr = wv >> 1, wc = wv & 1;
    const int row0 = (blockIdx.x >> 4) * 64, col0 = (blockIdx.x & 15) * 64;
    const int c0 = lane & 15, khalf = lane >> 4;

    const int sr = wv * 16 + (lane >> 2);
    const int sj = (lane & 3) ^ ((sr >> 1) & 3);
    const int sdst = (wv * 16) * 32 + lane * 8;
    const bf16s* srcA = &pooled[(size_t)(row0 + sr) * 1024 + sj * 8];
    const bf16s* srcB = &wpt[(size_t)(col0 + sr) * 1024 + sj * 8];

    f32x4 acc[2][2] = {};

    gload_lds16(srcA, &As[0][sdst]);
    gload_lds16(srcB, &Bs[0][sdst]);

    for (int t = 0; t < 32; ++t) {
        const int cur = t & 1;
        if (t < 31) {
            gload_lds16(srcA + (t + 1) * 32, &As[cur ^ 1][sdst]);
            gload_lds16(srcB + (t + 1) * 32, &Bs[cur ^ 1][sdst]);
            asm volatile("s_waitcnt vmcnt(2)" ::: "memory");
        } else {
            asm volatile("s_waitcnt vmcnt(0)" ::: "memory");
        }
        __builtin_amdgcn_s_barrier();
        __builtin_amdgcn_sched_barrier(0);
        #pragma unroll
        for (int mf = 0; mf < 2; ++mf) {
            int ra = wr * 32 + mf * 16 + c0;
            short8 av = *reinterpret_cast<const short8*>(
                &As[cur][ra * 32 + ((khalf ^ ((ra >> 1) & 3)) * 8)]);
            #pragma unroll
            for (int nf = 0; nf < 2; ++nf) {
                int rb = wc * 32 + nf * 16 + c0;
                short8 bv = *reinterpret_cast<const short8*>(
                    &Bs[cur][rb * 32 + ((khalf ^ ((rb >> 1) & 3)) * 8)]);
                acc[mf][nf] = __builtin_amdgcn_mfma_f32_16x16x32_bf16(av, bv, acc[mf][nf], 0, 0, 0);
            }
        }
        asm volatile("s_waitcnt lgkmcnt(0)" ::: "memory");
        __builtin_amdgcn_sched_barrier(0);
        __builtin_amdgcn_s_barrier();
    }
    #pragma unroll
    for (int mf = 0; mf < 2; ++mf)
        #pragma unroll
        for (int nf = 0; nf < 2; ++nf)
            #pragma unroll
            for (int reg = 0; reg < 4; ++reg) {
                int grow = row0 + wr * 32 + mf * 16 + khalf * 4 + reg;
                int gcol = col0 + wc * 32 + nf * 16 + c0;
                y[(size_t)grow * 1024 + gcol] = acc[mf][nf][reg] + bp[gcol];
            }
}

// ---------------------------------------------------------------------------
// LayerNorm + ELU + present-mask.
// ---------------------------------------------------------------------------
__global__ void k_lnelu(const float* __restrict__ y, const float* __restrict__ ln_g,
                        const float* __restrict__ ln_b, const int* __restrict__ counts,
                        float* __restrict__ outp)
{
    const int row = blockIdx.x;
    const int k = row & 127;
    const int tid = threadIdx.x;

    float4 v = *reinterpret_cast<const float4*>(&y[(size_t)row * 1024 + tid * 4]);
    float s = v.x + v.y + v.z + v.w;
    float ss = v.x * v.x + v.y * v.y + v.z * v.z + v.w * v.w;
    #pragma unroll
    for (int off = 32; off; off >>= 1) { s += __shfl_xor(s, off); ss += __shfl_xor(ss, off); }

    __shared__ float sbuf[4], ssbuf[4];
    int wv = tid >> 6;
    if ((tid & 63) == 0) { sbuf[wv] = s; ssbuf[wv] = ss; }
    __syncthreads();
    s = sbuf[0] + sbuf[1] + sbuf[2] + sbuf[3];
    ss = ssbuf[0] + ssbuf[1] + ssbuf[2] + ssbuf[3];

    float mu = s * (1.f / 1024.f);
    float var = ss * (1.f / 1024.f) - mu * mu;
    float rstd = rsqrtf(var + 1e-5f);

    bool pres = false;
    #pragma unroll
    for (int bb = 0; bb < 8; ++bb) pres = pres || (counts[bb * NBLK + k] > 0);

    float4 g4 = *reinterpret_cast<const float4*>(&ln_g[tid * 4]);
    float4 b4 = *reinterpret_cast<const float4*>(&ln_b[tid * 4]);
    float vals[4] = {v.x, v.y, v.z, v.w};
    float gs[4] = {g4.x, g4.y, g4.z, g4.w};
    float bs[4] = {b4.x, b4.y, b4.z, b4.w};
    float4 o;
    float* op = &o.x;
    #pragma unroll
    for (int j = 0; j < 4; ++j) {
        float t = (vals[j] - mu) * rstd * gs[j] + bs[j];
        t = (t > 0.f) ? t : expm1f(t);
        op[j] = pres ? t : 0.f;
    }
    *reinterpret_cast<float4*>(&outp[(size_t)row * 1024 + tid * 4]) = o;
}

// ---------------------------------------------------------------------------
extern "C" void kernel_launch(void* const* d_in, const int* in_sizes, int n_in,
                              void* d_out, int out_size, void* d_ws, size_t ws_size,
                              hipStream_t stream)
{
    const float* x      = (const float*)d_in[0];
    const int*   ct     = (const int*)d_in[1];
    const int*   bids   = (const int*)d_in[2];
    const unsigned char* pad = (const unsigned char*)d_in[3];
    const float* W1     = (const float*)d_in[4];
    const float* b1     = (const float*)d_in[5];
    const float* W2     = (const float*)d_in[6];
    const float* b2     = (const float*)d_in[7];
    const float* ct_emb = (const float*)d_in[8];
    const float* Wp     = (const float*)d_in[9];
    const float* bp     = (const float*)d_in[10];
    const float* ln_g   = (const float*)d_in[11];
    const float* ln_b   = (const float*)d_in[12];
    float* outF = (float*)d_out;

    char* ws = (char*)d_ws;
    bf16s* w1t    = (bf16s*)(ws + 0);          //  1,048,576
    bf16s* wpt    = (bf16s*)(ws + 1048576);    //  2,097,152 -> 3,145,728
    float* gate   = (float*)(ws + 3145728);    //    131,072 -> 3,276,800
    float* part   = (float*)(ws + 3276800);    //    524,288 -> 3,801,088 (2 used)
    float* mblk   = (float*)(ws + 3801088);
    float* wscal  = (float*)(ws + 3805184);
    int*   counts = (int*)  (ws + 3809280);
    int*   lists  = (int*)  (ws + 3813376);    //  1,048,576 -> 4,861,952
    bf16s* pooled = (bf16s*)(ws + 4861952);    //  2,097,152 -> 6,959,104
    float* ybuf   = (float*)(ws + 6959104);    //  4,194,304 -> 11,153,408

    k_tcvt2<<<dim3(16, 24), 256, 0, stream>>>(W1, Wp, w1t, wpt);
    k_gemmv<<<512, 256, 0, stream>>>(x, w1t, b1, W2, part);
    k_blocks<<<1024, 64, 0, stream>>>(bids, pad, part, b2, gate, ct, ct_emb,
                                      counts, mblk, wscal, lists,
                                      outF + (size_t)8 * NBLK * HDIM);
    k_pool<<<1024, 256, 0, stream>>>(x, gate, lists, counts, mblk, wscal, pooled);
    k_gemm2<<<256, 256, 0, stream>>>(pooled, wpt, bp, ybuf);
    k_lnelu<<<1024, 256, 0, stream>>>(ybuf, ln_g, ln_b, counts, outF);
}

// Round 16
// 124.902 us; speedup vs baseline: 1.0598x; 1.0098x over previous
//
#include <hip/hip_runtime.h>

// (B,N,H,NB,NCT) = (8,4096,1024,128,33), H/2 = 512
#define NTOK 4096
#define HDIM 1024
#define HHALF 512
#define NBLK 128
#define CAP 256

typedef __attribute__((ext_vector_type(8))) short short8;
typedef __attribute__((ext_vector_type(4))) float f32x4;
typedef short bf16s;

__device__ __forceinline__ short f2bf(float f) {
    unsigned u = __builtin_bit_cast(unsigned, f);
    u = (u + 0x7fffu + ((u >> 16) & 1u)) >> 16;   // RNE
    return (short)u;
}
__device__ __forceinline__ void gload_lds16(const void* g, void* l) {
    __builtin_amdgcn_global_load_lds(
        (const __attribute__((address_space(1))) unsigned int*)g,
        (__attribute__((address_space(3))) unsigned int*)l, 16, 0, 0);
}
__device__ __forceinline__ float fast_tanh(float v) {
    float e = __expf(2.0f * v);
    return 1.0f - 2.0f / (e + 1.0f);
}
// packed f32x2 -> bf16x2 (1 VALU op; RNE on gfx950). No builtin — inline asm.
__device__ __forceinline__ unsigned cvtpk(float lo, float hi) {
    unsigned r;
    asm("v_cvt_pk_bf16_f32 %0, %1, %2" : "=v"(r) : "v"(lo), "v"(hi));
    return r;
}

// ---------------------------------------------------------------------------
// Tiled transpose+convert for both weights.
// ---------------------------------------------------------------------------
__global__ void k_tcvt2(const float* __restrict__ W1, const float* __restrict__ Wp,
                        bf16s* __restrict__ w1t, bf16s* __restrict__ wpt) {
    __shared__ float tile[64][65];
    const int by = blockIdx.y;
    const float* in = (by < 8) ? W1 : Wp;
    bf16s* out = (by < 8) ? w1t : wpt;
    const int Nc = (by < 8) ? HHALF : HDIM;
    const int n0 = ((by < 8) ? by : (by - 8)) * 64;
    const int k0 = blockIdx.x * 64;
    const int tx = threadIdx.x & 63, ty = threadIdx.x >> 6;
    #pragma unroll
    for (int i = 0; i < 16; ++i) {
        int r = ty + i * 4;
        tile[r][tx] = in[(size_t)(k0 + r) * Nc + n0 + tx];
    }
    __syncthreads();
    #pragma unroll
    for (int i = 0; i < 16; ++i) {
        int r = ty + i * 4;
        out[(size_t)(n0 + r) * 1024 + k0 + tx] = f2bf(tile[tx][r]);
    }
}

// ---------------------------------------------------------------------------
// Gate GEMM v16 = R13 structure + two critical-path micro-fixes:
//  (a) A-conversion via v_cvt_pk_bf16_f32 (8 VALU ops vs 48 scalar f2bf)
//  (b) split ds_read/MFMA interleave: issue av[0..3]+bvv (8 reads), then
//      av[4..7]; lgkmcnt(4) certifies first 8 (in-order LDS FIFO) -> MFMA
//      cluster 1 runs while av[4..7] retire; lgkmcnt(0) -> cluster 2.
//      sched_barrier(0) after each counted wait (rule 18).
// Geometry/schedule unchanged (measured 81us): 128x256 tile, BK=32, 4 waves,
// acc[8][4], 48 KB LDS, 2 wgs/CU, ONE barrier per K-iter, counted-vmcnt
// staging by construction (FIFO: [B(t)4, Af32(t+1)4] -> CVTWR's implicit
// vmcnt(4) retires exactly those, keeps B(t+1) in flight).
// ---------------------------------------------------------------------------
__global__ __launch_bounds__(256, 2) void k_gemmv(
    const float* __restrict__ x, const bf16s* __restrict__ w1t,
    const float* __restrict__ b1, const float* __restrict__ w2,
    float* __restrict__ partial)
{
    __shared__ alignas(16) bf16s As[2][128 * 32];   //  16 KB
    __shared__ alignas(16) bf16s Bs[2][256 * 32];   //  32 KB

    const int tid = threadIdx.x;
    const int lane = tid & 63;
    const int wn = tid >> 6;                        // 0..3 (col group)
    const int phys = blockIdx.x;
    const int logical = (phys & 7) * 64 + (phys >> 3);  // 512 = 8*64 bijective
    const int rp = logical >> 1;                    // 0..255
    const int ctile = logical & 1;
    const int row0 = rp * 128;
    const int col0 = ctile * 256;
    const int c0 = lane & 15, khalf = lane >> 4;

    // ---- A staging (f32 -> regs -> cvt_pk -> ds_write, swizzled dest) ----
    const int ar = tid >> 1, ah = tid & 1;          // row 0..127, 16-col half
    const float* aF = &x[(size_t)(row0 + ar) * HDIM + ah * 16];
    const int akey = (ar >> 1) & 3;
    const int aslot0 = ((2 * ah) ^ akey) * 8;       // dest chunk slots (shorts)
    const int aslot1 = ((2 * ah + 1) ^ akey) * 8;
    const int arow32 = ar * 32;

    // ---- B staging (gll, pre-swizzled source) ----
    const int sj = (lane & 3) ^ ((lane >> 3) & 3);
    const bf16s* bS[4];
    int bdst[4];
    #pragma unroll
    for (int q = 0; q < 4; ++q) {
        int rb = wn * 64 + q * 16 + (lane >> 2);
        bS[q] = &w1t[(size_t)(col0 + rb) * HDIM + sj * 8];
        bdst[q] = (wn * 64 + q * 16) * 32 + lane * 8;
    }

    // ---- fragment read offsets ----
    const int fkey = (c0 >> 1) & 3;                 // == ((mf*16+c0)>>1)&3
    const int ach = (khalf ^ fkey) * 8;
    const int arA = c0 * 32 + ach;                  // + mf*16*32
    const int brB = (wn * 64 + c0) * 32 + ach;      // + nf*16*32 (same key math)

    f32x4 acc[8][4] = {};
    float4 rA0, rA1, rA2, rA3;

#define LOAD_RA(T) do {                                               \
        rA0 = *reinterpret_cast<const float4*>(aF + (T) * 32);        \
        rA1 = *reinterpret_cast<const float4*>(aF + (T) * 32 + 4);    \
        rA2 = *reinterpret_cast<const float4*>(aF + (T) * 32 + 8);    \
        rA3 = *reinterpret_cast<const float4*>(aF + (T) * 32 + 12);   \
    } while (0)
#define CVTWR(BUF) do {                                               \
        int4 w0_, w1_;                                                \
        w0_.x = (int)cvtpk(rA0.x, rA0.y);                             \
        w0_.y = (int)cvtpk(rA0.z, rA0.w);                             \
        w0_.z = (int)cvtpk(rA1.x, rA1.y);                             \
        w0_.w = (int)cvtpk(rA1.z, rA1.w);                             \
        w1_.x = (int)cvtpk(rA2.x, rA2.y);                             \
        w1_.y = (int)cvtpk(rA2.z, rA2.w);                             \
        w1_.z = (int)cvtpk(rA3.x, rA3.y);                             \
        w1_.w = (int)cvtpk(rA3.z, rA3.w);                             \
        *reinterpret_cast<int4*>(&As[BUF][arow32 + aslot0]) = w0_;    \
        *reinterpret_cast<int4*>(&As[BUF][arow32 + aslot1]) = w1_;    \
    } while (0)

    // ---- prologue: A(0)+B(0) -> buf0; rA = A(1) ----
    LOAD_RA(0);
    CVTWR(0);
    #pragma unroll
    for (int q = 0; q < 4; ++q)
        gload_lds16(bS[q], &Bs[0][bdst[q]]);
    LOAD_RA(1);

    for (int t = 0; t < 32; ++t) {
        const int c = t & 1;
        if (t < 31) {
            // stage tile t+1 into buf c^1 (certified dead: read at t-1, barrier since)
            #pragma unroll
            for (int q = 0; q < 4; ++q)
                gload_lds16(bS[q] + (t + 1) * 32, &Bs[c ^ 1][bdst[q]]);
            __builtin_amdgcn_sched_barrier(0);   // pin gll-before-CVTWR (keeps B(t+1) newest)
            CVTWR(c ^ 1);                        // implicit vmcnt(4): retires B(t)+Af32(t+1)
            if (t < 30) LOAD_RA(t + 2);
        } else {
            asm volatile("s_waitcnt vmcnt(0)" ::: "memory");
        }
        asm volatile("s_waitcnt lgkmcnt(0)" ::: "memory");  // A(t) (+just-issued) writes done
        __builtin_amdgcn_sched_barrier(0);
        __builtin_amdgcn_s_barrier();                       // tile t certified for all waves

        short8 av[8], bvv[4];
        // group 1: av[0..3] + bvv[0..3]  (8 ds_read_b128)
        #pragma unroll
        for (int mf = 0; mf < 4; ++mf)
            av[mf] = *reinterpret_cast<const short8*>(&As[c][arA + mf * 512]);
        #pragma unroll
        for (int nf = 0; nf < 4; ++nf)
            bvv[nf] = *reinterpret_cast<const short8*>(&Bs[c][brB + nf * 512]);
        __builtin_amdgcn_sched_barrier(0);                  // group1 issued first
        // group 2: av[4..7] (retire under MFMA cluster 1)
        #pragma unroll
        for (int mf = 4; mf < 8; ++mf)
            av[mf] = *reinterpret_cast<const short8*>(&As[c][arA + mf * 512]);
        asm volatile("s_waitcnt lgkmcnt(4)" ::: "memory");  // group1 complete (in-order FIFO)
        __builtin_amdgcn_sched_barrier(0);

        __builtin_amdgcn_s_setprio(1);
        #pragma unroll
        for (int nf = 0; nf < 4; ++nf)
            #pragma unroll
            for (int mf = 0; mf < 4; ++mf)
                acc[mf][nf] = __builtin_amdgcn_mfma_f32_16x16x32_bf16(av[mf], bvv[nf], acc[mf][nf], 0, 0, 0);
        asm volatile("s_waitcnt lgkmcnt(0)" ::: "memory");  // group2 complete
        __builtin_amdgcn_sched_barrier(0);
        #pragma unroll
        for (int nf = 0; nf < 4; ++nf)
            #pragma unroll
            for (int mf = 4; mf < 8; ++mf)
                acc[mf][nf] = __builtin_amdgcn_mfma_f32_16x16x32_bf16(av[mf], bvv[nf], acc[mf][nf], 0, 0, 0);
        __builtin_amdgcn_s_setprio(0);
        // no trailing barrier: my ds_reads are consumed before my next-iter barrier
        // arrival; writes to buf c resume only after TWO more top barriers (t+2).
    }
#undef LOAD_RA
#undef CVTWR

    // epilogue: per-row dot of tanh(h)*W2 over this wave's 64 cols.
    // gp[4][128] aliased into As (all LDS traffic drained: lgkm+barrier path).
    __syncthreads();
    float* gp = reinterpret_cast<float*>(&As[0][0]);
    float b1v[4], w2v[4];
    #pragma unroll
    for (int nf = 0; nf < 4; ++nf) {
        int gc = col0 + wn * 64 + nf * 16 + c0;
        b1v[nf] = b1[gc];
        w2v[nf] = w2[gc];
    }
    #pragma unroll
    for (int mf = 0; mf < 8; ++mf) {
        #pragma unroll
        for (int reg = 0; reg < 4; ++reg) {
            float s = 0.f;
            #pragma unroll
            for (int nf = 0; nf < 4; ++nf)
                s += fast_tanh(acc[mf][nf][reg] + b1v[nf]) * w2v[nf];
            s += __shfl_xor(s, 1); s += __shfl_xor(s, 2);
            s += __shfl_xor(s, 4); s += __shfl_xor(s, 8);
            if (c0 == 0) gp[wn * 128 + mf * 16 + khalf * 4 + reg] = s;
        }
    }
    __syncthreads();
    if (tid < 128)
        partial[(size_t)ctile * 32768 + row0 + tid] =
            gp[tid] + gp[128 + tid] + gp[256 + tid] + gp[384 + tid];
}

// ---------------------------------------------------------------------------
// Single-pass per-(b,block): sums the 2 gate partials for member tokens,
// online-softmax stats, ordered lists.
// ---------------------------------------------------------------------------
__global__ void k_blocks(const int* __restrict__ block_ids, const unsigned char* __restrict__ pad,
                         const float* __restrict__ part, const float* __restrict__ b2,
                         float* __restrict__ gate, const int* __restrict__ ct,
                         const float* __restrict__ ct_emb,
                         int* __restrict__ counts, float* __restrict__ mblk,
                         float* __restrict__ wscale, int* __restrict__ lists,
                         float* __restrict__ out_hasb)
{
    const int blk = blockIdx.x;
    const int b = blk >> 7, k = blk & 127;
    const int lane = threadIdx.x;
    const int base = b * NTOK;
    const int lbase = blk * CAP;
    const unsigned long long ltmask = (1ull << lane) - 1ull;
    const float b2v = b2[0];

    float m = -__builtin_inff();
    float s = 0.f;
    int pos = 0;
    for (int t0 = 0; t0 < NTOK; t0 += 64) {
        int t = t0 + lane;
        bool mt = (block_ids[base + t] == k) && (pad[base + t] == 0);
        unsigned long long mask = __ballot(mt);
        if (mt) {
            int r = base + t;
            float g = part[r] + part[32768 + r] + b2v;
            gate[r] = g;   // each valid token belongs to exactly one block
            int my = pos + __popcll(mask & ltmask);
            if (my < CAP) lists[lbase + my] = t;
            float mn = fmaxf(m, g);
            s = s * __expf(m - mn) + __expf(g - mn);
            m = mn;
        }
        pos += __popcll(mask);
    }
    #pragma unroll
    for (int off = 1; off < 64; off <<= 1) {
        float om = __shfl_xor(m, off);
        float os = __shfl_xor(s, off);
        float mn = fmaxf(m, om);
        float sa = (m == -__builtin_inff()) ? 0.f : s * __expf(m - mn);
        float sb = (om == -__builtin_inff()) ? 0.f : os * __expf(om - mn);
        s = sa + sb;
        m = mn;
    }
    if (lane == 0) {
        counts[blk] = pos;
        mblk[blk] = (pos > 0) ? m : 0.f;
        float mod = 1.0f + 0.1f * ct_emb[ct[b] * NBLK + k];
        wscale[blk] = (pos > 0 && s > 0.f) ? (mod / fmaxf(s, 1e-30f)) : 0.f;
        out_hasb[blk] = (pos > 0) ? 1.f : 0.f;
    }
}

// ---------------------------------------------------------------------------
// Pooling from f32 x (L3-resident; one-pass read at roofline).
// ---------------------------------------------------------------------------
__global__ void k_pool(const float* __restrict__ x, const float* __restrict__ gate,
                       const int* __restrict__ lists, const int* __restrict__ counts,
                       const float* __restrict__ mblk, const float* __restrict__ wscale,
                       bf16s* __restrict__ pooled)
{
    const int blk = blockIdx.x;
    const int b = blk >> 7;
    const int tid = threadIdx.x;
    const int base = b * NTOK;
    const int cnt = min(counts[blk], CAP);
    const int lbase = blk * CAP;
    const float m = mblk[blk], ws = wscale[blk];

    float4 acc = {0.f, 0.f, 0.f, 0.f};
    for (int i = 0; i < cnt; ++i) {
        int n = lists[lbase + i];
        float w = __expf(gate[base + n] - m);
        float4 xv = *reinterpret_cast<const float4*>(&x[(size_t)(base + n) * HDIM + tid * 4]);
        acc.x += w * xv.x; acc.y += w * xv.y; acc.z += w * xv.z; acc.w += w * xv.w;
    }
    short o[4] = {f2bf(acc.x * ws), f2bf(acc.y * ws), f2bf(acc.z * ws), f2bf(acc.w * ws)};
    *reinterpret_cast<int2*>(&pooled[(size_t)blk * HDIM + tid * 4]) =
        *reinterpret_cast<const int2*>(o);
}

// ---------------------------------------------------------------------------
// GEMM2: y = pooled @ Wp + bp. 1024^3. 64x64 tiles, 4 waves, dbuf + gll,
// counted-vmcnt schedule.
// ---------------------------------------------------------------------------
__global__ __launch_bounds__(256) void k_gemm2(
    const bf16s* __restrict__ pooled, const bf16s* __restrict__ wpt,
    const float* __restrict__ bp, float* __restrict__ y)
{
    __shared__ alignas(16) bf16s As[2][64 * 32];
    __shared__ alignas(16) bf16s Bs[2][64 * 32];
    const int tid = threadIdx.x;
    const int lane = tid & 63;
    const int wv = tid >> 6;
    const int wr = wv >> 1, wc = wv & 1;
    const int row0 = (blockIdx.x >> 4) * 64, col0 = (blockIdx.x & 15) * 64;
    const int c0 = lane & 15, khalf = lane >> 4;

    const int sr = wv * 16 + (lane >> 2);
    const int sj = (lane & 3) ^ ((sr >> 1) & 3);
    const int sdst = (wv * 16) * 32 + lane * 8;
    const bf16s* srcA = &pooled[(size_t)(row0 + sr) * 1024 + sj * 8];
    const bf16s* srcB = &wpt[(size_t)(col0 + sr) * 1024 + sj * 8];

    f32x4 acc[2][2] = {};

    gload_lds16(srcA, &As[0][sdst]);
    gload_lds16(srcB, &Bs[0][sdst]);

    for (int t = 0; t < 32; ++t) {
        const int cur = t & 1;
        if (t < 31) {
            gload_lds16(srcA + (t + 1) * 32, &As[cur ^ 1][sdst]);
            gload_lds16(srcB + (t + 1) * 32, &Bs[cur ^ 1][sdst]);
            asm volatile("s_waitcnt vmcnt(2)" ::: "memory");
        } else {
            asm volatile("s_waitcnt vmcnt(0)" ::: "memory");
        }
        __builtin_amdgcn_s_barrier();
        __builtin_amdgcn_sched_barrier(0);
        #pragma unroll
        for (int mf = 0; mf < 2; ++mf) {
            int ra = wr * 32 + mf * 16 + c0;
            short8 av = *reinterpret_cast<const short8*>(
                &As[cur][ra * 32 + ((khalf ^ ((ra >> 1) & 3)) * 8)]);
            #pragma unroll
            for (int nf = 0; nf < 2; ++nf) {
                int rb = wc * 32 + nf * 16 + c0;
                short8 bv = *reinterpret_cast<const short8*>(
                    &Bs[cur][rb * 32 + ((khalf ^ ((rb >> 1) & 3)) * 8)]);
                acc[mf][nf] = __builtin_amdgcn_mfma_f32_16x16x32_bf16(av, bv, acc[mf][nf], 0, 0, 0);
            }
        }
        asm volatile("s_waitcnt lgkmcnt(0)" ::: "memory");
        __builtin_amdgcn_sched_barrier(0);
        __builtin_amdgcn_s_barrier();
    }
    #pragma unroll
    for (int mf = 0; mf < 2; ++mf)
        #pragma unroll
        for (int nf = 0; nf < 2; ++nf)
            #pragma unroll
            for (int reg = 0; reg < 4; ++reg) {
                int grow = row0 + wr * 32 + mf * 16 + khalf * 4 + reg;
                int gcol = col0 + wc * 32 + nf * 16 + c0;
                y[(size_t)grow * 1024 + gcol] = acc[mf][nf][reg] + bp[gcol];
            }
}

// ---------------------------------------------------------------------------
// LayerNorm + ELU + present-mask.
// ---------------------------------------------------------------------------
__global__ void k_lnelu(const float* __restrict__ y, const float* __restrict__ ln_g,
                        const float* __restrict__ ln_b, const int* __restrict__ counts,
                        float* __restrict__ outp)
{
    const int row = blockIdx.x;
    const int k = row & 127;
    const int tid = threadIdx.x;

    float4 v = *reinterpret_cast<const float4*>(&y[(size_t)row * 1024 + tid * 4]);
    float s = v.x + v.y + v.z + v.w;
    float ss = v.x * v.x + v.y * v.y + v.z * v.z + v.w * v.w;
    #pragma unroll
    for (int off = 32; off; off >>= 1) { s += __shfl_xor(s, off); ss += __shfl_xor(ss, off); }

    __shared__ float sbuf[4], ssbuf[4];
    int wv = tid >> 6;
    if ((tid & 63) == 0) { sbuf[wv] = s; ssbuf[wv] = ss; }
    __syncthreads();
    s = sbuf[0] + sbuf[1] + sbuf[2] + sbuf[3];
    ss = ssbuf[0] + ssbuf[1] + ssbuf[2] + ssbuf[3];

    float mu = s * (1.f / 1024.f);
    float var = ss * (1.f / 1024.f) - mu * mu;
    float rstd = rsqrtf(var + 1e-5f);

    bool pres = false;
    #pragma unroll
    for (int bb = 0; bb < 8; ++bb) pres = pres || (counts[bb * NBLK + k] > 0);

    float4 g4 = *reinterpret_cast<const float4*>(&ln_g[tid * 4]);
    float4 b4 = *reinterpret_cast<const float4*>(&ln_b[tid * 4]);
    float vals[4] = {v.x, v.y, v.z, v.w};
    float gs[4] = {g4.x, g4.y, g4.z, g4.w};
    float bs[4] = {b4.x, b4.y, b4.z, b4.w};
    float4 o;
    float* op = &o.x;
    #pragma unroll
    for (int j = 0; j < 4; ++j) {
        float t = (vals[j] - mu) * rstd * gs[j] + bs[j];
        t = (t > 0.f) ? t : expm1f(t);
        op[j] = pres ? t : 0.f;
    }
    *reinterpret_cast<float4*>(&outp[(size_t)row * 1024 + tid * 4]) = o;
}

// ---------------------------------------------------------------------------
extern "C" void kernel_launch(void* const* d_in, const int* in_sizes, int n_in,
                              void* d_out, int out_size, void* d_ws, size_t ws_size,
                              hipStream_t stream)
{
    const float* x      = (const float*)d_in[0];
    const int*   ct     = (const int*)d_in[1];
    const int*   bids   = (const int*)d_in[2];
    const unsigned char* pad = (const unsigned char*)d_in[3];
    const float* W1     = (const float*)d_in[4];
    const float* b1     = (const float*)d_in[5];
    const float* W2     = (const float*)d_in[6];
    const float* b2     = (const float*)d_in[7];
    const float* ct_emb = (const float*)d_in[8];
    const float* Wp     = (const float*)d_in[9];
    const float* bp     = (const float*)d_in[10];
    const float* ln_g   = (const float*)d_in[11];
    const float* ln_b   = (const float*)d_in[12];
    float* outF = (float*)d_out;

    char* ws = (char*)d_ws;
    bf16s* w1t    = (bf16s*)(ws + 0);          //  1,048,576
    bf16s* wpt    = (bf16s*)(ws + 1048576);    //  2,097,152 -> 3,145,728
    float* gate   = (float*)(ws + 3145728);    //    131,072 -> 3,276,800
    float* part   = (float*)(ws + 3276800);    //    524,288 -> 3,801,088 (2 used)
    float* mblk   = (float*)(ws + 3801088);
    float* wscal  = (float*)(ws + 3805184);
    int*   counts = (int*)  (ws + 3809280);
    int*   lists  = (int*)  (ws + 3813376);    //  1,048,576 -> 4,861,952
    bf16s* pooled = (bf16s*)(ws + 4861952);    //  2,097,152 -> 6,959,104
    float* ybuf   = (float*)(ws + 6959104);    //  4,194,304 -> 11,153,408

    k_tcvt2<<<dim3(16, 24), 256, 0, stream>>>(W1, Wp, w1t, wpt);
    k_gemmv<<<512, 256, 0, stream>>>(x, w1t, b1, W2, part);
    k_blocks<<<1024, 64, 0, stream>>>(bids, pad, part, b2, gate, ct, ct_emb,
                                      counts, mblk, wscal, lists,
                                      outF + (size_t)8 * NBLK * HDIM);
    k_pool<<<1024, 256, 0, stream>>>(x, gate, lists, counts, mblk, wscal, pooled);
    k_gemm2<<<256, 256, 0, stream>>>(pooled, wpt, bp, ybuf);
    k_lnelu<<<1024, 256, 0, stream>>>(ybuf, ln_g, ln_b, counts, outF);
}